// Round 2
// baseline (36.220 us; speedup 1.0000x reference)
//
#include <hip/hip_runtime.h>

#define BATCH 131072
#define STEPS 100

// One thread owns ONE batch element. All state (2 membranes per layer) lives
// in registers; per step we store one float2 to each of the spk2 and mem2
// output slabs (8 B/lane -> 512 B contiguous per wave store, fully coalesced).
// 131072 threads = 2048 waves = 2 waves/SIMD for latency hiding on the
// store queue.
__global__ __launch_bounds__(256) void snn_lif_kernel(
    const float* __restrict__ x,
    const float* __restrict__ W1, const float* __restrict__ b1,
    const float* __restrict__ W2, const float* __restrict__ b2,
    float* __restrict__ out)
{
    const int tid = blockIdx.x * blockDim.x + threadIdx.x;  // [0, BATCH)

    // Tiny parameter arrays: scalar loads, L2-cached broadcast.
    const float w100 = W1[0], w101 = W1[1], w110 = W1[2], w111 = W1[3];
    const float b10  = b1[0], b11  = b1[1];
    const float w200 = W2[0], w201 = W2[1], w210 = W2[2], w211 = W2[3];
    const float b20  = b2[0], b21  = b2[1];

    // x[tid][0..1]
    const float2 xv = reinterpret_cast<const float2*>(x)[tid];

    // cur1 = x @ W1^T + b1  (constant across time, computed once)
    // NOTE: expression forms kept identical to the validated R1 kernel so the
    // spike/reset threshold comparisons stay bit-identical.
    const float c10 = xv.x * w100 + xv.y * w101 + b10;
    const float c11 = xv.x * w110 + xv.y * w111 + b11;

    float m10 = 0.f, m11 = 0.f;
    float m20 = 0.f, m21 = 0.f;

    float2* __restrict__ spk_out = reinterpret_cast<float2*>(out);
    float2* __restrict__ mem_out =
        reinterpret_cast<float2*>(out + (size_t)STEPS * BATCH * 2);

    const int slab = BATCH;  // float2s per time slab

#pragma unroll 4
    for (int t = 0; t < STEPS; ++t) {
        float r, s10, s11;

        // ---- layer-1 LIF (reset from previous mem, integrate, fire) ----
        r = (m10 > 1.0f) ? 1.0f : 0.0f;
        m10 = 0.99f * m10 + c10 - r;
        s10 = (m10 > 1.0f) ? 1.0f : 0.0f;

        r = (m11 > 1.0f) ? 1.0f : 0.0f;
        m11 = 0.99f * m11 + c11 - r;
        s11 = (m11 > 1.0f) ? 1.0f : 0.0f;

        // ---- cur2 = spk1 @ W2^T + b2 ----
        const float c20 = s10 * w200 + s11 * w201 + b20;
        const float c21 = s10 * w210 + s11 * w211 + b21;

        // ---- layer-2 LIF ----
        float2 sp;

        r = (m20 > 1.0f) ? 1.0f : 0.0f;
        m20 = 0.99f * m20 + c20 - r;
        sp.x = (m20 > 1.0f) ? 1.0f : 0.0f;

        r = (m21 > 1.0f) ? 1.0f : 0.0f;
        m21 = 0.99f * m21 + c21 - r;
        sp.y = (m21 > 1.0f) ? 1.0f : 0.0f;

        const float2 mm = make_float2(m20, m21);

        spk_out[(size_t)t * slab + tid] = sp;
        mem_out[(size_t)t * slab + tid] = mm;
    }
}

extern "C" void kernel_launch(void* const* d_in, const int* in_sizes, int n_in,
                              void* d_out, int out_size, void* d_ws, size_t ws_size,
                              hipStream_t stream) {
    const float* x  = (const float*)d_in[0];
    const float* W1 = (const float*)d_in[1];
    const float* b1 = (const float*)d_in[2];
    const float* W2 = (const float*)d_in[3];
    const float* b2 = (const float*)d_in[4];
    float* out = (float*)d_out;

    const int threads = 256;
    const int blocks = BATCH / threads;  // 512 blocks
    snn_lif_kernel<<<blocks, threads, 0, stream>>>(x, W1, b1, W2, b2, out);
}